// Round 7
// baseline (192.273 us; speedup 1.0000x reference)
//
#include <hip/hip_runtime.h>
#include <hip/hip_bf16.h>
#include <stdint.h>

// out[4096,4096] = x[4096,2048] @ matrix[0,4096,2048]^T   (fp32 in/out)
// R10: cast pass unchanged. GEMM: R9's B-direct (B fragments straight from
// global/L2, no LDS for B; LDS pipe 3300->2100 cyc/tile-pair < MFMA 2483)
// with R9's wait bug fixed: ks-major MFMA order (c1 r0-3ks0, c2 r4-7ks0,
// c3 r0-3ks1, c4 r4-7ks1) lets bF halves reload one tile early WITHOUT
// extra regs: BL0(t+1) mid-tile (after c2), BL1(t+1)+STAGE(t+2) at end.
// Counted waits by construction: c1 waits bF0(t) = vmcnt(12) (BL1(t)+
// STAGE(t+1) stay in flight); c3 waits bF1(t) = vmcnt(12); explicit
// vmcnt(4) before the one barrier/tile retires STAGE(t+1) (1 tile old,
// free) keeping BL0(t+1) outstanding. No wait targets a load issued <1
// tile prior (R9's bug: bF was newest -> every tile ate L2 gather latency).
// No setprio (confound-free vs R3). A keeps R3's XOR chunk swizzle
// (0 conflicts) + m89 C/D layout. 2 blocks/CU (64KB LDS, ~110 VGPR).

#define GAS __attribute__((address_space(1)))
#define LAS __attribute__((address_space(3)))

typedef __bf16 bf16x8 __attribute__((ext_vector_type(8)));
typedef float f32x4 __attribute__((ext_vector_type(4)));

static __device__ __forceinline__ unsigned short f2bf(float f) {
  union { float f; uint32_t u; } a; a.f = f;
  uint32_t u = a.u;
  u += 0x7FFFu + ((u >> 16) & 1u);   // round-to-nearest-even
  return (unsigned short)(u >> 16);
}

__global__ void cvt_f32_to_bf16(const float4* __restrict__ x,
                                const float4* __restrict__ m,
                                ushort4* __restrict__ xo,
                                ushort4* __restrict__ mo) {
  const int i = blockIdx.x * blockDim.x + threadIdx.x;
  const float4* __restrict__ src = blockIdx.y ? m : x;
  ushort4* __restrict__ dst      = blockIdx.y ? mo : xo;
  float4 v = src[i];
  ushort4 o;
  o.x = f2bf(v.x); o.y = f2bf(v.y); o.z = f2bf(v.z); o.w = f2bf(v.w);
  dst[i] = o;
}

#define MFMA16(a, b, c) __builtin_amdgcn_mfma_f32_16x16x32_bf16((a), (b), (c), 0, 0, 0)
#define SB0 __builtin_amdgcn_sched_barrier(0)

// C[M,N] = A[M,K]*B[N,K]^T, M=4096, N=4096, K=2048. 256 threads = 4 waves.
// Block tile 256x128; wave (wm=wave&1, wn=wave>>1) owns rows wm*128..+128,
// cols wn*64..+64 as acc[8][4] of 16x16x32 frags. BK=64, NT=32.
// A: LDS dbuf As[2][256*64] (64KB), XOR chunk swizzle, global_load_lds.
// B: direct-to-VGPR. bF half ks: lane(l15,quad), frag j reads
//    B[bN+wn*64+j*16+l15][t*64+ks*32+quad*8 ..+8) -- MFMA B layout
//    (R9-verified numerically).
__global__ __launch_bounds__(256, 2)
void gemm_bt_bf16(const unsigned short* __restrict__ A,
                  const unsigned short* __restrict__ B,
                  float* __restrict__ C) {
  constexpr int K  = 2048;
  constexpr int N  = 4096;
  constexpr int NT = K / 64;   // 32 K-tiles

  __shared__ __align__(16) unsigned short As[2][256 * 64];   // 64 KB

  const int tid  = threadIdx.x;
  const int wave = tid >> 6;
  const int lane = tid & 63;
  const int wm   = wave & 1;
  const int wn   = wave >> 1;
  const int bM   = blockIdx.y * 256;
  const int bN   = blockIdx.x * 128;

  const int quad = lane >> 4;   // 0..3
  const int l15  = lane & 15;
  const int mx   = l15 & 7;

  // A staging (R3's): wave covers rows [wave*64, wave*64+64), 8 insts of
  // 8 rows; lane -> row lr, pre-swizzled source chunk lc.
  const int lr = lane >> 3;
  const int lc = (lane & 7) ^ lr;
  const size_t aBase = (size_t)(bM + wave * 64 + lr) * K + lc * 8;
  const int aLds = wave * 64 * 64;   // elems

  // A fragment reads: physical chunk = (ks*4+quad)^mx.
  const int aOff = (wm * 128 + l15) * 64;
  const int ko0  = ((0 * 4 + quad) ^ mx) << 3;
  const int ko1  = ((1 * 4 + quad) ^ mx) << 3;

  // B fragment base: row = bN + wn*64 + l15 (+j*16), k = quad*8 (+t*64+ks*32)
  const unsigned short* bPtr = B + (size_t)(bN + wn * 64 + l15) * K + quad * 8;

  f32x4 acc[8][4] = {};
  bf16x8 aF[8], bF0[4], bF1[4];

#define STAGE(tau, pp) do {                                                                \
    const size_t kk_ = (size_t)(tau) * 64;                                                 \
    _Pragma("unroll")                                                                      \
    for (int u = 0; u < 8; ++u)                                                            \
      __builtin_amdgcn_global_load_lds((const GAS void*)(A + aBase + kk_ + (size_t)u * 8 * K), \
                                       (LAS void*)(&As[pp][aLds + u * 512]), 16, 0, 0);    \
  } while (0)

#define BL0(tau) do {                                                                      \
    const size_t kk_ = (size_t)(tau) * 64;                                                 \
    _Pragma("unroll")                                                                      \
    for (int j = 0; j < 4; ++j)                                                            \
      bF0[j] = *(const bf16x8*)(bPtr + (size_t)j * 16 * K + kk_);                          \
  } while (0)

#define BL1(tau) do {                                                                      \
    const size_t kk_ = (size_t)(tau) * 64;                                                 \
    _Pragma("unroll")                                                                      \
    for (int j = 0; j < 4; ++j)                                                            \
      bF1[j] = *(const bf16x8*)(bPtr + (size_t)j * 16 * K + kk_ + 32);                     \
  } while (0)

  // Prologue. Issue order matters for counted waits:
  // STAGE(0), BL0(0), BL1(0), STAGE(1); vmcnt(16) retires STAGE(0) only.
  STAGE(0, 0);
  BL0(0);
  BL1(0);
  STAGE(1, 1);
  asm volatile("s_waitcnt vmcnt(16)" ::: "memory");
  SB0;
  __builtin_amdgcn_s_barrier();
  SB0;

#pragma unroll 1
  for (int t = 0; t < NT; ++t) {
    const unsigned short* Ap = As[t & 1];

    // ---- ds_read aF ks0 (8 x b128) ----
#pragma unroll
    for (int i = 0; i < 8; ++i)
      aF[i] = *(const bf16x8*)(Ap + aOff + i * 1024 + ko0);
    // ---- c1: rows 0-3, ks0 (16 MFMA; waits bF0(t) = vmcnt(12)) ----
#pragma unroll
    for (int i = 0; i < 4; ++i)
#pragma unroll
      for (int j = 0; j < 4; ++j)
        acc[i][j] = MFMA16(aF[i], bF0[j], acc[i][j]);
    // ---- c2: rows 4-7, ks0 (16 MFMA) ----
#pragma unroll
    for (int i = 4; i < 8; ++i)
#pragma unroll
      for (int j = 0; j < 4; ++j)
        acc[i][j] = MFMA16(aF[i], bF0[j], acc[i][j]);
    SB0;
    // ---- mid-tile: reload bF0 for t+1 (bF0 dead after c2) ----
    if (t + 1 < NT) BL0(t + 1);
    SB0;
    // ---- ds_read aF ks1 in-place (WAR after c1/c2 issue) ----
#pragma unroll
    for (int i = 0; i < 8; ++i)
      aF[i] = *(const bf16x8*)(Ap + aOff + i * 1024 + ko1);
    // ---- c3: rows 0-3, ks1 (waits bF1(t) = vmcnt(12)) ----
#pragma unroll
    for (int i = 0; i < 4; ++i)
#pragma unroll
      for (int j = 0; j < 4; ++j)
        acc[i][j] = MFMA16(aF[i], bF1[j], acc[i][j]);
    // ---- c4: rows 4-7, ks1 ----
#pragma unroll
    for (int i = 4; i < 8; ++i)
#pragma unroll
      for (int j = 0; j < 4; ++j)
        acc[i][j] = MFMA16(aF[i], bF1[j], acc[i][j]);
    SB0;
    // ---- end of tile: one barrier; counted vmcnt(4) retires STAGE(t+1)
    //      (1 tile in flight) while keeping BL0(t+1) outstanding ----
    if (t + 1 < NT) {
      asm volatile("s_waitcnt lgkmcnt(0)" ::: "memory");   // my A reads done
      asm volatile("s_waitcnt vmcnt(4)" ::: "memory");     // STAGE(t+1) landed
      SB0;
      __builtin_amdgcn_s_barrier();                        // buf swap + WAR
      SB0;
      BL1(t + 1);                                          // bF1 dead after c4
      if (t + 2 < NT) STAGE(t + 2, t & 1);
      SB0;
    }
  }
#undef STAGE
#undef BL0
#undef BL1

  // Epilogue: C/D layout col=lane&15, row=quad*4+reg (m89-verified).
#pragma unroll
  for (int i = 0; i < 8; ++i) {
    const int row0 = bM + wm * 128 + i * 16 + quad * 4;
#pragma unroll
    for (int j = 0; j < 4; ++j) {
      const int col = bN + wn * 64 + j * 16 + l15;
#pragma unroll
      for (int tt = 0; tt < 4; ++tt)
        C[(size_t)(row0 + tt) * N + col] = acc[i][j][tt];
    }
  }
}

extern "C" void kernel_launch(void* const* d_in, const int* in_sizes, int n_in,
                              void* d_out, int out_size, void* d_ws, size_t ws_size,
                              hipStream_t stream) {
  const float* x   = (const float*)d_in[0];   // [4096, 2048]
  const float* mat = (const float*)d_in[1];   // [1, 4096, 2048]
  float* out = (float*)d_out;                 // [4096, 4096]

  constexpr size_t ELEMS = 4096ull * 2048ull;
  unsigned short* xb = (unsigned short*)d_ws;
  unsigned short* mb = xb + ELEMS;

  dim3 cgrid((unsigned)(ELEMS / 4 / 256), 2);
  cvt_f32_to_bf16<<<cgrid, 256, 0, stream>>>((const float4*)x, (const float4*)mat,
                                             (ushort4*)xb, (ushort4*)mb);

  // 512 blocks: grid.x = N/128 = 32, grid.y = M/256 = 16 -> 2 blocks/CU.
  // Natural order keeps each XCD's B working set L2-resident (~2MB).
  gemm_bt_bf16<<<dim3(32, 16), 256, 0, stream>>>(xb, mb, out);
}

// Round 8
// 168.952 us; speedup vs baseline: 1.1380x; 1.1380x over previous
//
#include <hip/hip_runtime.h>
#include <hip/hip_bf16.h>
#include <stdint.h>

// out[4096,4096] = x[4096,2048] @ matrix[0,4096,2048]^T   (fp32 in/out)
// R11: cast pass unchanged. GEMM = R3's exact structure (256x128 block tile,
// single-buffered 48KB LDS, 2 syncthreads/K-tile, XOR chunk swizzle, grid
// 32x16) re-partitioned into 8 WAVES of 64x64 (was 4 waves of 128x64).
// Rationale: R3-R10 post-mortems show per-SIMD matrix need = 2483 cyc/K-tile
// vs 5175 wall with only 2 waves/SIMD resident; LDS BW (~200cyc/CU/tile) and
// supply are not the wall -- latency bubbles are, and schedule-only variants
// (R4-R8) can't fill them with 2 contexts. 8 waves x 2 blocks = 4 waves/SIMD
// doubles the independent streams per SIMD. acc shrinks to [4][4] (64 AGPR);
// __launch_bounds__(512,4) forces <=128 unified regs so 16 waves/CU fit.
// B-direct (R9/R10) reverted: scattered B gathers were the regression.
// All verified layouts retained: m89 C/D mapping, chunk swizzle (0 conflicts).

#define GAS __attribute__((address_space(1)))
#define LAS __attribute__((address_space(3)))

typedef __bf16 bf16x8 __attribute__((ext_vector_type(8)));
typedef float f32x4 __attribute__((ext_vector_type(4)));

static __device__ __forceinline__ unsigned short f2bf(float f) {
  union { float f; uint32_t u; } a; a.f = f;
  uint32_t u = a.u;
  u += 0x7FFFu + ((u >> 16) & 1u);   // round-to-nearest-even
  return (unsigned short)(u >> 16);
}

__global__ void cvt_f32_to_bf16(const float4* __restrict__ x,
                                const float4* __restrict__ m,
                                ushort4* __restrict__ xo,
                                ushort4* __restrict__ mo) {
  const int i = blockIdx.x * blockDim.x + threadIdx.x;
  const float4* __restrict__ src = blockIdx.y ? m : x;
  ushort4* __restrict__ dst      = blockIdx.y ? mo : xo;
  float4 v = src[i];
  ushort4 o;
  o.x = f2bf(v.x); o.y = f2bf(v.y); o.z = f2bf(v.z); o.w = f2bf(v.w);
  dst[i] = o;
}

#define MFMA16(a, b, c) __builtin_amdgcn_mfma_f32_16x16x32_bf16((a), (b), (c), 0, 0, 0)

// C[M,N] = A[M,K]*B[N,K]^T, M=4096, N=4096, K=2048. 512 threads = 8 waves.
// Block tile 256x128; wave (wr=wave>>1, wc=wave&1) owns rows wr*64..+64,
// cols wc*64..+64 as acc[4][4] of 16x16x32 frags. BK=64, NT=32.
// LDS: As[256*64]+Bs[128*64] single-buffered (48KB); global chunk c (16B)
// of row r stored at physical chunk c^(r&7).
// Per K-tile: stage (4A+2B gload_lds per wave) | sync | 2 ks x {read bF[4],
// {read aF_i; 4 MFMA} x4} | sync.  2 blocks/CU x 8 waves = 4 waves/SIMD.
__global__ __launch_bounds__(512, 4)
void gemm_bt_bf16(const unsigned short* __restrict__ A,
                  const unsigned short* __restrict__ B,
                  float* __restrict__ C) {
  constexpr int K = 2048;
  constexpr int N = 4096;

  __shared__ __align__(16) unsigned short As[256 * 64];   // 32 KB
  __shared__ __align__(16) unsigned short Bs[128 * 64];   // 16 KB

  const int tid  = threadIdx.x;
  const int wave = tid >> 6;
  const int lane = tid & 63;
  const int wr   = wave >> 1;   // 0..3 (row block of 64)
  const int wc   = wave & 1;    // 0..1 (col block of 64)
  const int bM   = blockIdx.y * 256;
  const int bN   = blockIdx.x * 128;

  const int quad = lane >> 4;   // 0..3
  const int l15  = lane & 15;
  const int mx   = l15 & 7;     // = row&7 for all fragment rows (x16 offsets)

  // Staging: wave w covers A rows [w*32, w*32+32) in 4 insts of 8 rows and
  // B rows [w*16, w*16+16) in 2 insts. lane -> row lr, pre-swizzled chunk lc.
  const int lr = lane >> 3;
  const int lc = (lane & 7) ^ lr;
  const size_t aBase = (size_t)(bM + wave * 32 + lr) * K + lc * 8;
  const size_t bBase = (size_t)(bN + wave * 16 + lr) * K + lc * 8;
  const int aLds = wave * 32 * 64;   // elems
  const int bLds = wave * 16 * 64;

  // Fragment read offsets (elems). Physical chunk = (ks*4+quad)^mx.
  // Fragment row = wr*64 + i*16 + l15 -> row&7 == l15&7 == mx (64,16 = 0 mod 8).
  const int aOff = (wr * 64 + l15) * 64;
  const int bOff = (wc * 64 + l15) * 64;

  f32x4 acc[4][4] = {};

  for (int k0 = 0; k0 < K; k0 += 64) {
#pragma unroll
    for (int t = 0; t < 4; ++t)
      __builtin_amdgcn_global_load_lds((const GAS void*)(A + aBase + k0 + t * 8 * K),
                                       (LAS void*)(As + aLds + t * 512), 16, 0, 0);
#pragma unroll
    for (int t = 0; t < 2; ++t)
      __builtin_amdgcn_global_load_lds((const GAS void*)(B + bBase + k0 + t * 8 * K),
                                       (LAS void*)(Bs + bLds + t * 512), 16, 0, 0);
    __syncthreads();

#pragma unroll
    for (int ks = 0; ks < 2; ++ks) {
      const int koff = ((ks * 4 + quad) ^ mx) << 3;
      bf16x8 bF[4];
#pragma unroll
      for (int j = 0; j < 4; ++j)
        bF[j] = *(const bf16x8*)(Bs + bOff + j * 1024 + koff);
#pragma unroll
      for (int i = 0; i < 4; ++i) {
        const bf16x8 aF = *(const bf16x8*)(As + aOff + i * 1024 + koff);
#pragma unroll
        for (int j = 0; j < 4; ++j)
          acc[i][j] = MFMA16(aF, bF[j], acc[i][j]);
      }
    }
    __syncthreads();
  }

  // Epilogue: C/D layout col=lane&15, row=quad*4+reg (m89-verified).
#pragma unroll
  for (int i = 0; i < 4; ++i) {
    const int row0 = bM + wr * 64 + i * 16 + quad * 4;
#pragma unroll
    for (int j = 0; j < 4; ++j) {
      const int col = bN + wc * 64 + j * 16 + l15;
#pragma unroll
      for (int t = 0; t < 4; ++t)
        C[(size_t)(row0 + t) * N + col] = acc[i][j][t];
    }
  }
}

extern "C" void kernel_launch(void* const* d_in, const int* in_sizes, int n_in,
                              void* d_out, int out_size, void* d_ws, size_t ws_size,
                              hipStream_t stream) {
  const float* x   = (const float*)d_in[0];   // [4096, 2048]
  const float* mat = (const float*)d_in[1];   // [1, 4096, 2048]
  float* out = (float*)d_out;                 // [4096, 4096]

  constexpr size_t ELEMS = 4096ull * 2048ull;
  unsigned short* xb = (unsigned short*)d_ws;
  unsigned short* mb = xb + ELEMS;

  dim3 cgrid((unsigned)(ELEMS / 4 / 256), 2);
  cvt_f32_to_bf16<<<cgrid, 256, 0, stream>>>((const float4*)x, (const float4*)mat,
                                             (ushort4*)xb, (ushort4*)mb);

  // 512 blocks: grid.x = N/128 = 32, grid.y = M/256 = 16 -> 2 blocks/CU,
  // 16 waves/CU = 4 waves/SIMD.
  gemm_bt_bf16<<<dim3(32, 16), 512, 0, stream>>>(xb, mb, out);
}